// Round 2
// baseline (314.009 us; speedup 1.0000x reference)
//
#include <hip/hip_runtime.h>

// LatticeStyleConv R5: StyleGAN2-modulated 5-point stencil conv, bf16 MFMA.
// bs=8, ci=co=256, H=W=128.
//
// R5 changes vs R4:
//  * conv3: 8x64 output tile per block (was 4x64). Each wave owns 2 rows ->
//    the per-wave 20KB/ck A-frag (weight) global re-read now feeds 160 MFMAs
//    instead of 80: af vmem per output HALVED, stage per output -16%.
//    Theory: R3/R4 counters (MfmaUtil 36.5 flat across occupancy 2-4 blk/CU
//    and prefetch on/off) show the vmem path (af 80KB + stage 30KB per
//    block-ck vs 3100 cyc MFMA) is the co-bottleneck, not latency.
//    Single-buffered (R4 proved dbuf null), LDS 10x5632=56320B, 2 blk/CU,
//    grid 1024 = 2 clean generations.
// Layouts (guide §3 m89/m91): A[m=l15][k=quad*8+j]; B[n=l15][k=quad*8+j];
// C/D col=l15, row=quad*4+reg.

typedef short v8s __attribute__((ext_vector_type(8)));
typedef float v4f __attribute__((ext_vector_type(4)));
typedef int   v4i __attribute__((ext_vector_type(4)));

#define BS 8
#define CI 256
#define CO 256
#define HH 128
#define WW 128

#define WF_CK 10240          // shorts per (b,ot,ck) A-frag slab
#define RSTR_B 5632          // conv3 LDS row stride bytes (88 px * 64B)
#define RSTR_I 1408          // ... in ints

#define GLOAD_LDS16(g, l)                                                  \
    __builtin_amdgcn_global_load_lds(                                      \
        (__attribute__((address_space(1))) void*)(g),                      \
        (__attribute__((address_space(3))) void*)(l), 16, 0, 0)

__device__ __forceinline__ unsigned short f2bf(float f) {
    unsigned u = __builtin_bit_cast(unsigned, f);
    u += 0x7FFFu + ((u >> 16) & 1u);   // RNE (inputs finite)
    return (unsigned short)(u >> 16);
}

// -------- fused prep: blocks [0,2048) weight-prep, [2048,10240) x-transpose --
__global__ __launch_bounds__(256) void prep_kernel(const float* __restrict__ x,
                                                   const float* __restrict__ y,
                                                   const float* __restrict__ wgt,
                                                   short* __restrict__ wfrag,
                                                   unsigned int* __restrict__ xt) {
    __shared__ float tr[32 * 132];     // [c][px], stride 132 floats
    __shared__ float red[4];

    if (blockIdx.x < 2048) {
        // ---- wprep2: fused demod + modulated weights -> A-frag layout ----
        const int bo = blockIdx.x;
        const int b = bo >> 8, o = bo & 255;
        const int ci = threadIdx.x;
        const float ym = y[b * CI + ci] + 1.0f;
        const float* wp = wgt + (o * CI + ci) * 5;
        float w[5];
        float s2 = 0.f;
        #pragma unroll
        for (int s = 0; s < 5; ++s) { w[s] = wp[s]; s2 += w[s] * w[s]; }
        float ss = ym * ym * s2;
        #pragma unroll
        for (int off = 32; off > 0; off >>= 1) ss += __shfl_down(ss, off);
        if ((threadIdx.x & 63) == 0) red[threadIdx.x >> 6] = ss;
        __syncthreads();
        const float tot = red[0] + red[1] + red[2] + red[3];
        const float scale = ym * rsqrtf(tot + 1e-6f);
        const int ot = o >> 6, mt = (o >> 4) & 3, m = o & 15;
        const int ck = ci >> 5, quad = (ci >> 3) & 3, j = ci & 7;
        size_t base = ((size_t)(b * 4 + ot) * 8 + ck) * WF_CK + quad * 128 + m * 8 + j;
        #pragma unroll
        for (int s = 0; s < 5; ++s)
            wfrag[base + (size_t)(s * 4 + mt) * 512] = (short)f2bf(w[s] * scale);
    } else {
        // ---- xprep: x fp32 [b][ci][h][w] -> bf16 x_t[b][ck][h][w][32ch] ----
        const int bid = blockIdx.x - 2048;     // (b*8 + ck)*128 + h
        const int b  = bid >> 10;
        const int ck = (bid >> 7) & 7;
        const int h  = bid & 127;
        const int tid = threadIdx.x;
        // vectorized loads: 4 x dwordx4 per thread, b128 LDS writes
        #pragma unroll
        for (int i = 0; i < 4; ++i) {
            int q  = tid + i * 256;            // 0..1023
            int c  = q >> 5;                   // 0..31
            int qp = q & 31;                   // 0..31 (px quad)
            v4f v = *(const v4f*)&x[((size_t)(b * CI + ck * 32 + c) * HH + h) * WW
                                    + qp * 4];
            *(v4f*)&tr[c * 132 + qp * 4] = v;
        }
        __syncthreads();
        const int px = tid >> 1, half = tid & 1;
        unsigned pk[8];
        #pragma unroll
        for (int k = 0; k < 8; ++k) {
            float f0 = tr[(half * 16 + 2 * k)     * 132 + px];
            float f1 = tr[(half * 16 + 2 * k + 1) * 132 + px];
            pk[k] = (unsigned)f2bf(f0) | ((unsigned)f2bf(f1) << 16);
        }
        unsigned int* dst = xt + ((size_t)((b * 8 + ck) * 16384 + h * 128 + px)) * 16
                               + half * 8;
        *(v4i*)dst       = (v4i){(int)pk[0], (int)pk[1], (int)pk[2], (int)pk[3]};
        *(v4i*)(dst + 4) = (v4i){(int)pk[4], (int)pk[5], (int)pk[6], (int)pk[7]};
    }
}

// -------- wprep2 standalone (mid-path fallback) --------
__global__ __launch_bounds__(256) void wprep2_kernel(const float* __restrict__ y,
                                                     const float* __restrict__ wgt,
                                                     short* __restrict__ wfrag) {
    const int bo = blockIdx.x;
    const int b = bo >> 8, o = bo & 255;
    const int ci = threadIdx.x;
    const float ym = y[b * CI + ci] + 1.0f;
    const float* wp = wgt + (o * CI + ci) * 5;
    float w[5];
    float s2 = 0.f;
    #pragma unroll
    for (int s = 0; s < 5; ++s) { w[s] = wp[s]; s2 += w[s] * w[s]; }
    float ss = ym * ym * s2;
    #pragma unroll
    for (int off = 32; off > 0; off >>= 1) ss += __shfl_down(ss, off);
    __shared__ float red[4];
    if ((threadIdx.x & 63) == 0) red[threadIdx.x >> 6] = ss;
    __syncthreads();
    const float tot = red[0] + red[1] + red[2] + red[3];
    const float scale = ym * rsqrtf(tot + 1e-6f);
    const int ot = o >> 6, mt = (o >> 4) & 3, m = o & 15;
    const int ck = ci >> 5, quad = (ci >> 3) & 3, j = ci & 7;
    size_t base = ((size_t)(b * 4 + ot) * 8 + ck) * WF_CK + quad * 128 + m * 8 + j;
    #pragma unroll
    for (int s = 0; s < 5; ++s)
        wfrag[base + (size_t)(s * 4 + mt) * 512] = (short)f2bf(w[s] * scale);
}

// -------- conv3: 8x64 tile, single-buffered staging, 2 rows/wave --------
__global__ __launch_bounds__(256, 2) void conv3_kernel(const char* __restrict__ xt,
                                                       const short* __restrict__ wfrag,
                                                       float* __restrict__ out) {
    const int b     = blockIdx.z;
    const int ot    = blockIdx.y;
    const int oBase = ot * 64;
    const int st    = blockIdx.x;          // 16 row-tiles x 2 col-tiles
    const int r0    = (st >> 1) * 8;
    const int c0    = (st & 1) * 64;
    const bool left = (c0 == 0);

    const int tid  = threadIdx.x;
    const int wid  = tid >> 6;
    const int lane = tid & 63;
    const int l15  = lane & 15;
    const int quad = lane >> 4;

    __shared__ __align__(16) int xs[10 * RSTR_I];    // 56320 B

    v4f acc[2][4][4];
    #pragma unroll
    for (int r = 0; r < 2; ++r)
        #pragma unroll
        for (int a = 0; a < 4; ++a)
            #pragma unroll
            for (int n = 0; n < 4; ++n) acc[r][a][n] = (v4f){0.f, 0.f, 0.f, 0.f};

    // ---- one-time zeroing of never-loaded halo regions ----
    const v4i z4 = (v4i){0, 0, 0, 0};
    if (r0 == 0)
        for (int i = tid; i < 264; i += 256) *(v4i*)&xs[i * 4] = z4;              // row 0, px0..65
    if (r0 == HH - 8)
        for (int i = tid; i < 264; i += 256) *(v4i*)&xs[9 * RSTR_I + i * 4] = z4; // row 9
    if (left && tid < 40) *(v4i*)&xs[(tid >> 2) * RSTR_I + (tid & 3) * 4] = z4;   // px0 col, rows 0..9
    // first chunk's __syncthreads covers these writes

    const short* wfb = wfrag + (size_t)(b * 4 + ot) * 8 * WF_CK;
    const bool rz = (!left) && (l15 == 15);          // right-edge gc=128 mask
    const int gstartB = left ? 0 : (c0 - 1) * 64;    // byte offset of first loaded px
    const int lshift  = left ? 64 : 0;

    const int dh[5] = {-1, 0, 0, 0, 1};
    const int dw[5] = { 0,-1, 0, 1, 0};

    for (int ck = 0; ck < 8; ++ck) {
        const char* planep = xt + (((size_t)(b * 8 + ck)) << 20);
        // ---- staging: rows rr in {wid, wid+4, wid+8}, 5x1024B per row ----
        #pragma unroll
        for (int rsel = 0; rsel < 3; ++rsel) {
            int rr = wid + rsel * 4;
            if (rr < 10) {
                bool skip = (r0 == 0 && rr == 0) || (r0 == HH - 8 && rr == 9);
                if (!skip) {
                    int gr = r0 - 1 + rr;
                    const char* gb = planep + (size_t)gr * 8192 + gstartB + lane * 16;
                    char* lb = (char*)xs + rr * RSTR_B + lshift;
                    #pragma unroll
                    for (int t = 0; t < 5; ++t)
                        GLOAD_LDS16(gb + t * 1024, lb + t * 1024);
                }
            }
        }
        __syncthreads();   // drains vmcnt: x tile ready

        const short* wfc = wfb + (size_t)ck * WF_CK;
        #pragma unroll
        for (int s = 0; s < 5; ++s) {
            const int xc0 = 1 + dw[s];
            v8s af[4];
            #pragma unroll
            for (int mt = 0; mt < 4; ++mt)
                af[mt] = *(const v8s*)(wfc + (size_t)((s * 4 + mt) * 4 + quad) * 128
                                           + l15 * 8);
            #pragma unroll
            for (int r = 0; r < 2; ++r) {
                const int xrow = 2 * wid + r + 1 + dh[s];
                #pragma unroll
                for (int nt = 0; nt < 4; ++nt) {
                    v4i bi = *(const v4i*)&xs[xrow * RSTR_I
                                              + (nt * 16 + l15 + xc0) * 16 + quad * 4];
                    if (s == 3 && nt == 3) { if (rz) bi = z4; }   // gc=128 -> 0
                    v8s bfr = __builtin_bit_cast(v8s, bi);
                    #pragma unroll
                    for (int mt = 0; mt < 4; ++mt)
                        acc[r][mt][nt] = __builtin_amdgcn_mfma_f32_16x16x32_bf16(
                            af[mt], bfr, acc[r][mt][nt], 0, 0, 0);
                }
            }
        }
        __syncthreads();   // protect xs before next chunk's DMA
    }

    #pragma unroll
    for (int r = 0; r < 2; ++r) {
        const int row = r0 + 2 * wid + r;
        #pragma unroll
        for (int mt = 0; mt < 4; ++mt)
            #pragma unroll
            for (int nt = 0; nt < 4; ++nt)
                #pragma unroll
                for (int rg = 0; rg < 4; ++rg) {
                    int o = oBase + mt * 16 + quad * 4 + rg;
                    int c = c0 + nt * 16 + l15;
                    out[((size_t)(b * CO + o) * HH + row) * WW + c] = acc[r][mt][nt][rg];
                }
    }
}

// ================= R2 conv (mid fallback) =================
__global__ __launch_bounds__(256, 4) void conv_kernel(const float* __restrict__ x,
                                                      const short* __restrict__ wfrag,
                                                      float* __restrict__ out) {
    const int b     = blockIdx.z;
    const int ot    = blockIdx.y;
    const int oBase = ot * 64;
    const int st    = blockIdx.x;
    const int r0    = (st >> 1) * 4;
    const int c0    = (st & 1) * 64;
    const int tid  = threadIdx.x;
    const int wid  = tid >> 6;
    const int lane = tid & 63;
    const int l15  = lane & 15;
    const int quad = lane >> 4;
    #define PXS 20
    __shared__ __align__(16) int xs[6 * 66 * PXS];
    v4f acc[4][4];
    #pragma unroll
    for (int a = 0; a < 4; ++a)
        #pragma unroll
        for (int n = 0; n < 4; ++n) acc[a][n] = (v4f){0.f, 0.f, 0.f, 0.f};
    const int row = r0 + wid;
    const short* wfb = wfrag + (size_t)(b * 4 + ot) * 8 * WF_CK;
    const int dh[5] = {-1, 0, 0, 0, 1};
    const int dw[5] = { 0,-1, 0, 1, 0};
    for (int ck = 0; ck < 8; ++ck) {
        const int ic0 = ck * 32;
        #pragma unroll
        for (int t = 0; t < 6; ++t) {
            int idx = tid + t * 256;
            int cp  = idx & 15;
            int tmp = idx >> 4;
            int cq  = tmp & 15;
            int rr  = tmp >> 4;
            int gr  = r0 - 1 + rr;
            v4f a0 = (v4f){0.f, 0.f, 0.f, 0.f}, a1 = a0;
            if (gr >= 0 && gr < HH) {
                const float* xp = x + ((size_t)(b * CI + ic0 + cp * 2) * HH + gr) * WW
                                    + (c0 + cq * 4);
                a0 = *(const v4f*)xp;
                a1 = *(const v4f*)(xp + HH * WW);
            }
            int base = (rr * 66 + cq * 4 + 1) * PXS + cp;
            #pragma unroll
            for (int k = 0; k < 4; ++k)
                xs[base + k * PXS] =
                    (int)((unsigned)f2bf(a0[k]) | ((unsigned)f2bf(a1[k]) << 16));
        }
        if (tid < 192) {
            int cp   = tid & 15;
            int tmp  = tid >> 4;
            int side = (tmp >= 6) ? 1 : 0;
            int rr   = tmp - 6 * side;
            int gr   = r0 - 1 + rr;
            int gc   = side ? (c0 + 64) : (c0 - 1);
            float v0 = 0.f, v1 = 0.f;
            if (gr >= 0 && gr < HH && gc >= 0 && gc < WW) {
                const float* xp = x + ((size_t)(b * CI + ic0 + cp * 2) * HH + gr) * WW + gc;
                v0 = xp[0];
                v1 = xp[HH * WW];
            }
            int col = side ? 65 : 0;
            xs[(rr * 66 + col) * PXS + cp] =
                (int)((unsigned)f2bf(v0) | ((unsigned)f2bf(v1) << 16));
        }
        __syncthreads();
        const short* wfc = wfb + (size_t)ck * WF_CK;
        #pragma unroll
        for (int s = 0; s < 5; ++s) {
            const int xrow = wid + 1 + dh[s];
            const int xc0  = 1 + dw[s];
            v8s af[4];
            #pragma unroll
            for (int mt = 0; mt < 4; ++mt)
                af[mt] = *(const v8s*)(wfc + (size_t)((s * 4 + mt) * 4 + quad) * 128
                                           + l15 * 8);
            #pragma unroll
            for (int nt = 0; nt < 4; ++nt) {
                int px = xrow * 66 + nt * 16 + l15 + xc0;
                v4i bi = *(const v4i*)&xs[px * PXS + quad * 4];
                v8s bfr = __builtin_bit_cast(v8s, bi);
                #pragma unroll
                for (int mt = 0; mt < 4; ++mt)
                    acc[mt][nt] = __builtin_amdgcn_mfma_f32_16x16x32_bf16(
                        af[mt], bfr, acc[mt][nt], 0, 0, 0);
            }
        }
        __syncthreads();
    }
    #pragma unroll
    for (int mt = 0; mt < 4; ++mt)
        #pragma unroll
        for (int nt = 0; nt < 4; ++nt)
            #pragma unroll
            for (int r = 0; r < 4; ++r) {
                int o = oBase + mt * 16 + quad * 4 + r;
                int c = c0 + nt * 16 + l15;
                out[((size_t)(b * CO + o) * HH + row) * WW + c] = acc[mt][nt][r];
            }
}

// ================= R1 min fallback =================
__global__ __launch_bounds__(256) void demod_kernel(const float* __restrict__ y,
                                                    const float* __restrict__ wgt,
                                                    float* __restrict__ dbuf) {
    const int bo = blockIdx.x;
    const int b = bo >> 8, o = bo & 255;
    const int i = threadIdx.x;
    const float* wp = wgt + (o * CI + i) * 5;
    const float ym = y[b * CI + i] + 1.0f;
    float s2 = 0.f;
    #pragma unroll
    for (int s = 0; s < 5; ++s) { float w = wp[s]; s2 += w * w; }
    float val = ym * ym * s2;
    #pragma unroll
    for (int off = 32; off > 0; off >>= 1) val += __shfl_down(val, off);
    __shared__ float red[4];
    if ((threadIdx.x & 63) == 0) red[threadIdx.x >> 6] = val;
    __syncthreads();
    if (threadIdx.x == 0) dbuf[bo] = rsqrtf(red[0] + red[1] + red[2] + red[3] + 1e-6f);
}

__global__ __launch_bounds__(256) void conv_kernel_fb(const float* __restrict__ x,
                                                      const float* __restrict__ y,
                                                      const float* __restrict__ wgt,
                                                      const float* __restrict__ dbuf,
                                                      float* __restrict__ out) {
    const int b     = blockIdx.z;
    const int oBase = blockIdx.y * 64;
    const int st    = blockIdx.x;
    const int r0    = (st >> 1) * 4;
    const int c0    = (st & 1) * 64;
    const int tid  = threadIdx.x;
    const int wid  = tid >> 6;
    const int lane = tid & 63;
    const int l15  = lane & 15;
    const int quad = lane >> 4;
    __shared__ int   xs4[16 * 412];
    __shared__ short wlds[5 * 4 * 4 * 16 * 8];
    v4f acc[4][4];
    #pragma unroll
    for (int a = 0; a < 4; ++a)
        #pragma unroll
        for (int n = 0; n < 4; ++n) acc[a][n] = (v4f){0.f, 0.f, 0.f, 0.f};
    const int row = r0 + wid;
    for (int ic0 = 0; ic0 < CI; ic0 += 32) {
        for (int t = 0; t < 25; ++t) {
            int idx = tid + t * 256;
            if (idx < 6336) {
                int cp  = idx / 396;
                int rem = idx - cp * 396;
                int rr  = rem / 66;
                int cc  = rem - rr * 66;
                int gr  = r0 - 1 + rr;
                int gc  = c0 - 1 + cc;
                float v0 = 0.f, v1 = 0.f;
                if (gr >= 0 && gr < HH && gc >= 0 && gc < WW) {
                    const float* xp = x + ((size_t)(b * CI + ic0 + cp * 2) * HH + gr) * WW + gc;
                    v0 = xp[0];
                    v1 = xp[HH * WW];
                }
                xs4[cp * 412 + rr * 68 + cc] =
                    (int)((unsigned)f2bf(v0) | ((unsigned)f2bf(v1) << 16));
            }
        }
        #pragma unroll
        for (int p = 0; p < 8; ++p) {
            int pidx = tid + p * 256;
            int ol = pidx >> 5;
            int il = pidx & 31;
            int o  = oBase + ol;
            int ci = ic0 + il;
            float scale = (y[b * CI + ci] + 1.0f) * dbuf[b * CO + o];
            const float* wp = wgt + (o * CI + ci) * 5;
            int base = (((ol >> 4) * 4 + (il >> 3)) * 16 + (ol & 15)) * 8 + (il & 7);
            #pragma unroll
            for (int s = 0; s < 5; ++s)
                wlds[base + s * (4 * 4 * 16 * 8)] = (short)f2bf(wp[s] * scale);
        }
        __syncthreads();
        const int dh[5] = {-1, 0, 0, 0, 1};
        const int dw[5] = { 0,-1, 0, 1, 0};
        #pragma unroll
        for (int s = 0; s < 5; ++s) {
            int xrow = wid + 1 + dh[s];
            int xcb  = l15 + 1 + dw[s];
            v8s af[4];
            #pragma unroll
            for (int mt = 0; mt < 4; ++mt)
                af[mt] = *(const v8s*)&wlds[(((s * 4 + mt) * 4 + quad) * 16 + l15) * 8];
            #pragma unroll
            for (int nt = 0; nt < 4; ++nt) {
                v4i bi;
                #pragma unroll
                for (int p = 0; p < 4; ++p)
                    bi[p] = xs4[(quad * 4 + p) * 412 + xrow * 68 + nt * 16 + xcb];
                v8s bfr = __builtin_bit_cast(v8s, bi);
                #pragma unroll
                for (int mt = 0; mt < 4; ++mt)
                    acc[mt][nt] = __builtin_amdgcn_mfma_f32_16x16x32_bf16(
                        af[mt], bfr, acc[mt][nt], 0, 0, 0);
            }
        }
        __syncthreads();
    }
    #pragma unroll
    for (int mt = 0; mt < 4; ++mt)
        #pragma unroll
        for (int nt = 0; nt < 4; ++nt)
            #pragma unroll
            for (int r = 0; r < 4; ++r) {
                int o = oBase + mt * 16 + quad * 4 + r;
                int c = c0 + nt * 16 + l15;
                out[((size_t)(b * CO + o) * HH + row) * WW + c] = acc[mt][nt][r];
            }
}

extern "C" void kernel_launch(void* const* d_in, const int* in_sizes, int n_in,
                              void* d_out, int out_size, void* d_ws, size_t ws_size,
                              hipStream_t stream) {
    const float* x   = (const float*)d_in[0];
    const float* y   = (const float*)d_in[1];
    const float* wgt = (const float*)d_in[2];
    float* out = (float*)d_out;

    const size_t WF_BYTES = (size_t)BS * 4 * 8 * WF_CK * sizeof(short);  // 5.25 MB
    const size_t XT_OFF   = WF_BYTES + 8192;
    const size_t XT_BYTES = (size_t)BS * 8 * 16384 * 64;                 // 64 MB
    const size_t NEED_FULL = XT_OFF + XT_BYTES + 1024;                   // OOB slack
    const size_t NEED_MID  = WF_BYTES + 8192;

    short* wfrag = (short*)d_ws;

    if (ws_size >= NEED_FULL) {
        unsigned int* xt = (unsigned int*)((char*)d_ws + XT_OFF);
        prep_kernel<<<dim3(2048 + BS * 8 * HH), dim3(256), 0, stream>>>(
            x, y, wgt, wfrag, xt);
        conv3_kernel<<<dim3(32, CO / 64, BS), dim3(256), 0, stream>>>(
            (const char*)xt, wfrag, out);
    } else if (ws_size >= NEED_MID) {
        wprep2_kernel<<<dim3(BS * CO), dim3(256), 0, stream>>>(y, wgt, wfrag);
        conv_kernel<<<dim3(64, CO / 64, BS), dim3(256), 0, stream>>>(x, wfrag, out);
    } else {
        float* dbuf = (float*)d_ws;   // 8 KB
        demod_kernel<<<dim3(BS * CO), dim3(256), 0, stream>>>(y, wgt, dbuf);
        conv_kernel_fb<<<dim3(64, CO / 64, BS), dim3(256), 0, stream>>>(x, y, wgt, dbuf, out);
    }
}

// Round 3
// 310.744 us; speedup vs baseline: 1.0105x; 1.0105x over previous
//
#include <hip/hip_runtime.h>

// LatticeStyleConv R6: StyleGAN2-modulated 5-point stencil conv, bf16 MFMA.
// bs=8, ci=co=256, H=W=128.
//
// R6 changes vs R5 (theory: R3/R4/R5 all ~95us because the 2-barrier
// structure SERIALIZES MFMA 99k + LDS 81k + VALU 37k cyc/CU; counted-vmcnt
// pipeline + conflict-free LDS overlaps them):
//  * conv3: 4x64 tile, double-buffered LDS (67584B, 2 blk/CU), counted-vmcnt
//    schedule, ONE raw s_barrier per ck, never vmcnt(0) in the loop:
//      af(20 loads) -> vmcnt(20) [stage_ck landed] -> s_barrier ->
//      stage(ck+1) (8 DMA) -> vmcnt(8) [af in regs, stage stays in flight] ->
//      ds_read + 80 MFMA.
//    Staging is branch-free/uniform (8 chunks per wave ALWAYS): edge rows
//    clamped to [0,127] and ZEROED IN REGISTERS (tz/bz masks, like rz); left
//    halo px-1 loaded as garbage and masked (lz). 30 real chunks + 2 benign
//    duplicate chunks = 32.
//  * LDS XOR-swizzle (T2, rule #21 both-sides): granule g ^= (g>>3)&7.
//    Old pattern put each 16-lane phase on only 2 of 8 bank-groups (4 extra
//    cyc/read, 5.25M conflicts). Swizzle -> uniform 2-way = free (m136).
//    Applied as pre-swizzled GLOBAL source addr (DMA dest stays linear) +
//    swizzled ds_read addr.
// Layouts (guide §3 m89/m91): A[m=l15][k=quad*8+j]; B[n=l15][k=quad*8+j];
// C/D col=l15, row=quad*4+reg.

typedef short v8s __attribute__((ext_vector_type(8)));
typedef float v4f __attribute__((ext_vector_type(4)));
typedef int   v4i __attribute__((ext_vector_type(4)));

#define BS 8
#define CI 256
#define CO 256
#define HH 128
#define WW 128

#define WF_CK 10240          // shorts per (b,ot,ck) A-frag slab
#define RSTR_B 5632          // conv3 LDS row stride bytes (88 px * 64B)
#define RSTR_I 1408          // ... in ints
#define XBUF_I (6 * RSTR_I)  // ints per x-tile buffer
#define XBUF_B (6 * RSTR_B)  // bytes per x-tile buffer

#define GLOAD_LDS16(g, l)                                                  \
    __builtin_amdgcn_global_load_lds(                                      \
        (__attribute__((address_space(1))) void*)(g),                      \
        (__attribute__((address_space(3))) void*)(l), 16, 0, 0)

__device__ __forceinline__ unsigned short f2bf(float f) {
    unsigned u = __builtin_bit_cast(unsigned, f);
    u += 0x7FFFu + ((u >> 16) & 1u);   // RNE (inputs finite)
    return (unsigned short)(u >> 16);
}

// -------- fused prep: blocks [0,2048) weight-prep, [2048,10240) x-transpose --
__global__ __launch_bounds__(256) void prep_kernel(const float* __restrict__ x,
                                                   const float* __restrict__ y,
                                                   const float* __restrict__ wgt,
                                                   short* __restrict__ wfrag,
                                                   unsigned int* __restrict__ xt) {
    __shared__ float tr[32 * 132];     // [c][px], stride 132 floats
    __shared__ float red[4];

    if (blockIdx.x < 2048) {
        // ---- wprep2: fused demod + modulated weights -> A-frag layout ----
        const int bo = blockIdx.x;
        const int b = bo >> 8, o = bo & 255;
        const int ci = threadIdx.x;
        const float ym = y[b * CI + ci] + 1.0f;
        const float* wp = wgt + (o * CI + ci) * 5;
        float w[5];
        float s2 = 0.f;
        #pragma unroll
        for (int s = 0; s < 5; ++s) { w[s] = wp[s]; s2 += w[s] * w[s]; }
        float ss = ym * ym * s2;
        #pragma unroll
        for (int off = 32; off > 0; off >>= 1) ss += __shfl_down(ss, off);
        if ((threadIdx.x & 63) == 0) red[threadIdx.x >> 6] = ss;
        __syncthreads();
        const float tot = red[0] + red[1] + red[2] + red[3];
        const float scale = ym * rsqrtf(tot + 1e-6f);
        const int ot = o >> 6, mt = (o >> 4) & 3, m = o & 15;
        const int ck = ci >> 5, quad = (ci >> 3) & 3, j = ci & 7;
        size_t base = ((size_t)(b * 4 + ot) * 8 + ck) * WF_CK + quad * 128 + m * 8 + j;
        #pragma unroll
        for (int s = 0; s < 5; ++s)
            wfrag[base + (size_t)(s * 4 + mt) * 512] = (short)f2bf(w[s] * scale);
    } else {
        // ---- xprep: x fp32 [b][ci][h][w] -> bf16 x_t[b][ck][h][w][32ch] ----
        const int bid = blockIdx.x - 2048;     // (b*8 + ck)*128 + h
        const int b  = bid >> 10;
        const int ck = (bid >> 7) & 7;
        const int h  = bid & 127;
        const int tid = threadIdx.x;
        // vectorized loads: 4 x dwordx4 per thread, b128 LDS writes
        #pragma unroll
        for (int i = 0; i < 4; ++i) {
            int q  = tid + i * 256;            // 0..1023
            int c  = q >> 5;                   // 0..31
            int qp = q & 31;                   // 0..31 (px quad)
            v4f v = *(const v4f*)&x[((size_t)(b * CI + ck * 32 + c) * HH + h) * WW
                                    + qp * 4];
            *(v4f*)&tr[c * 132 + qp * 4] = v;
        }
        __syncthreads();
        const int px = tid >> 1, half = tid & 1;
        unsigned pk[8];
        #pragma unroll
        for (int k = 0; k < 8; ++k) {
            float f0 = tr[(half * 16 + 2 * k)     * 132 + px];
            float f1 = tr[(half * 16 + 2 * k + 1) * 132 + px];
            pk[k] = (unsigned)f2bf(f0) | ((unsigned)f2bf(f1) << 16);
        }
        unsigned int* dst = xt + ((size_t)((b * 8 + ck) * 16384 + h * 128 + px)) * 16
                               + half * 8;
        *(v4i*)dst       = (v4i){(int)pk[0], (int)pk[1], (int)pk[2], (int)pk[3]};
        *(v4i*)(dst + 4) = (v4i){(int)pk[4], (int)pk[5], (int)pk[6], (int)pk[7]};
    }
}

// -------- wprep2 standalone (mid-path fallback) --------
__global__ __launch_bounds__(256) void wprep2_kernel(const float* __restrict__ y,
                                                     const float* __restrict__ wgt,
                                                     short* __restrict__ wfrag) {
    const int bo = blockIdx.x;
    const int b = bo >> 8, o = bo & 255;
    const int ci = threadIdx.x;
    const float ym = y[b * CI + ci] + 1.0f;
    const float* wp = wgt + (o * CI + ci) * 5;
    float w[5];
    float s2 = 0.f;
    #pragma unroll
    for (int s = 0; s < 5; ++s) { w[s] = wp[s]; s2 += w[s] * w[s]; }
    float ss = ym * ym * s2;
    #pragma unroll
    for (int off = 32; off > 0; off >>= 1) ss += __shfl_down(ss, off);
    __shared__ float red[4];
    if ((threadIdx.x & 63) == 0) red[threadIdx.x >> 6] = ss;
    __syncthreads();
    const float tot = red[0] + red[1] + red[2] + red[3];
    const float scale = ym * rsqrtf(tot + 1e-6f);
    const int ot = o >> 6, mt = (o >> 4) & 3, m = o & 15;
    const int ck = ci >> 5, quad = (ci >> 3) & 3, j = ci & 7;
    size_t base = ((size_t)(b * 4 + ot) * 8 + ck) * WF_CK + quad * 128 + m * 8 + j;
    #pragma unroll
    for (int s = 0; s < 5; ++s)
        wfrag[base + (size_t)(s * 4 + mt) * 512] = (short)f2bf(w[s] * scale);
}

// -------- conv3: counted-vmcnt double-buffered pipeline, swizzled LDS --------
__global__ __launch_bounds__(256, 2) void conv3_kernel(const char* __restrict__ xt,
                                                       const short* __restrict__ wfrag,
                                                       float* __restrict__ out) {
    const int b     = blockIdx.z;
    const int ot    = blockIdx.y;
    const int oBase = ot * 64;
    const int st    = blockIdx.x;          // 32 row-tiles x 2 col-tiles
    const int r0    = (st >> 1) * 4;
    const int c0    = (st & 1) * 64;
    const bool left = (c0 == 0);

    const int tid  = threadIdx.x;
    const int wid  = tid >> 6;
    const int lane = tid & 63;
    const int l15  = lane & 15;
    const int quad = lane >> 4;

    __shared__ __align__(16) int xs[2 * XBUF_I];    // 67584 B

    v4f acc[4][4];
    #pragma unroll
    for (int a = 0; a < 4; ++a)
        #pragma unroll
        for (int n = 0; n < 4; ++n) acc[a][n] = (v4f){0.f, 0.f, 0.f, 0.f};

    const int row = r0 + wid;
    const short* wfb = wfrag + (size_t)(b * 4 + ot) * 8 * WF_CK;
    const int gstartB = (c0 - 1) * 64;               // uniform (left: px -1 garbage)

    // register-side halo masks (no LDS pre-zeroing; staging is branch-free)
    const bool rzm  = (!left) && (l15 == 15);        // right edge: s==3,nt==3 slot65=px128
    const bool lzm  = left && (l15 == 0);            // left edge:  s==1,nt==0 slot0 =px-1
    const bool topz = (r0 == 0)      && (wid == 0);  // s==0 tap of output row 0
    const bool botz = (r0 == HH - 4) && (wid == 3);  // s==4 tap of output row 127
    const v4i z4 = (v4i){0, 0, 0, 0};

    const int dh[5] = {-1, 0, 0, 0, 1};
    const int dw[5] = { 0,-1, 0, 1, 0};

    // ---- precompute staging offsets: 32 chunks (30 real + 2 dup), 8/wave ----
    int goff[8], loff[8];
    #pragma unroll
    for (int k = 0; k < 8; ++k) {
        int q  = wid + 4 * k;                 // 0..31
        int qq = q < 30 ? q : q - 2;          // dummies duplicate row5 t3,t4
        int rr = qq / 5, t = qq - rr * 5;
        int gr = r0 - 1 + rr;
        gr = gr < 0 ? 0 : (gr > 127 ? 127 : gr);   // clamp; masked in regs
        int l  = t * 64 + lane;               // LDS granule within row
        int gx = l ^ ((l >> 3) & 7);          // pre-swizzled global source
        goff[k] = gr * 8192 + gstartB + gx * 16;
        loff[k] = rr * RSTR_B + l * 16;       // linear DMA dest
    }

    // ---- precompute swizzled B-read offsets (ck-invariant) ----
    int boff[5][4];
    #pragma unroll
    for (int s = 0; s < 5; ++s) {
        const int xrow = wid + 1 + dh[s];
        const int xc0  = 1 + dw[s];
        #pragma unroll
        for (int nt = 0; nt < 4; ++nt) {
            int slot = nt * 16 + l15 + xc0;
            int gran = slot * 4 + quad;
            int sg   = gran ^ ((gran >> 3) & 7);
            boff[s][nt] = xrow * RSTR_I + sg * 4;
        }
    }

    auto stage = [&](int ckk, int bufsel) {
        const char* planep = xt + (((size_t)(b * 8 + ckk)) << 20);
        char* lbase = (char*)xs + bufsel * XBUF_B;
        #pragma unroll
        for (int k = 0; k < 8; ++k)
            GLOAD_LDS16(planep + goff[k], lbase + loff[k]);
    };

    v8s af[20];
    auto load_af = [&](int ck) {
        const short* wfc = wfb + (size_t)ck * WF_CK;
        #pragma unroll
        for (int sm = 0; sm < 20; ++sm)
            af[sm] = *(const v8s*)(wfc + (size_t)(sm * 4 + quad) * 128 + l15 * 8);
    };

    auto conv_step = [&](const int* xb) {
        #pragma unroll
        for (int s = 0; s < 5; ++s) {
            #pragma unroll
            for (int nt = 0; nt < 4; ++nt) {
                v4i bi = *(const v4i*)&xb[boff[s][nt]];
                if (s == 0)            { if (topz) bi = z4; }
                if (s == 4)            { if (botz) bi = z4; }
                if (s == 1 && nt == 0) { if (lzm)  bi = z4; }
                if (s == 3 && nt == 3) { if (rzm)  bi = z4; }
                v8s bfr = __builtin_bit_cast(v8s, bi);
                #pragma unroll
                for (int mt = 0; mt < 4; ++mt)
                    acc[mt][nt] = __builtin_amdgcn_mfma_f32_16x16x32_bf16(
                        af[s * 4 + mt], bfr, acc[mt][nt], 0, 0, 0);
            }
        }
    };

    // ---- pipeline: one barrier/ck, loads always in flight, no vmcnt(0) ----
    stage(0, 0);
    for (int ck = 0; ck < 7; ++ck) {
        load_af(ck);                                   // 20 loads (youngest)
        asm volatile("s_waitcnt vmcnt(20)" ::: "memory");  // stage(ck) landed
        __builtin_amdgcn_s_barrier();                  // all waves' tile ready
        stage(ck + 1, (ck + 1) & 1);                   // 8 DMA, stays in flight
        asm volatile("s_waitcnt vmcnt(8)" ::: "memory");   // af in regs
        conv_step(xs + (ck & 1) * XBUF_I);
    }
    load_af(7);
    asm volatile("s_waitcnt vmcnt(20)" ::: "memory");
    __builtin_amdgcn_s_barrier();
    asm volatile("s_waitcnt vmcnt(0)" ::: "memory");
    conv_step(xs + XBUF_I);

    #pragma unroll
    for (int mt = 0; mt < 4; ++mt)
        #pragma unroll
        for (int nt = 0; nt < 4; ++nt)
            #pragma unroll
            for (int r = 0; r < 4; ++r) {
                int o = oBase + mt * 16 + quad * 4 + r;
                int c = c0 + nt * 16 + l15;
                out[((size_t)(b * CO + o) * HH + row) * WW + c] = acc[mt][nt][r];
            }
}

// ================= R2 conv (mid fallback) =================
__global__ __launch_bounds__(256, 4) void conv_kernel(const float* __restrict__ x,
                                                      const short* __restrict__ wfrag,
                                                      float* __restrict__ out) {
    const int b     = blockIdx.z;
    const int ot    = blockIdx.y;
    const int oBase = ot * 64;
    const int st    = blockIdx.x;
    const int r0    = (st >> 1) * 4;
    const int c0    = (st & 1) * 64;
    const int tid  = threadIdx.x;
    const int wid  = tid >> 6;
    const int lane = tid & 63;
    const int l15  = lane & 15;
    const int quad = lane >> 4;
    #define PXS 20
    __shared__ __align__(16) int xs[6 * 66 * PXS];
    v4f acc[4][4];
    #pragma unroll
    for (int a = 0; a < 4; ++a)
        #pragma unroll
        for (int n = 0; n < 4; ++n) acc[a][n] = (v4f){0.f, 0.f, 0.f, 0.f};
    const int row = r0 + wid;
    const short* wfb = wfrag + (size_t)(b * 4 + ot) * 8 * WF_CK;
    const int dh[5] = {-1, 0, 0, 0, 1};
    const int dw[5] = { 0,-1, 0, 1, 0};
    for (int ck = 0; ck < 8; ++ck) {
        const int ic0 = ck * 32;
        #pragma unroll
        for (int t = 0; t < 6; ++t) {
            int idx = tid + t * 256;
            int cp  = idx & 15;
            int tmp = idx >> 4;
            int cq  = tmp & 15;
            int rr  = tmp >> 4;
            int gr  = r0 - 1 + rr;
            v4f a0 = (v4f){0.f, 0.f, 0.f, 0.f}, a1 = a0;
            if (gr >= 0 && gr < HH) {
                const float* xp = x + ((size_t)(b * CI + ic0 + cp * 2) * HH + gr) * WW
                                    + (c0 + cq * 4);
                a0 = *(const v4f*)xp;
                a1 = *(const v4f*)(xp + HH * WW);
            }
            int base = (rr * 66 + cq * 4 + 1) * PXS + cp;
            #pragma unroll
            for (int k = 0; k < 4; ++k)
                xs[base + k * PXS] =
                    (int)((unsigned)f2bf(a0[k]) | ((unsigned)f2bf(a1[k]) << 16));
        }
        if (tid < 192) {
            int cp   = tid & 15;
            int tmp  = tid >> 4;
            int side = (tmp >= 6) ? 1 : 0;
            int rr   = tmp - 6 * side;
            int gr   = r0 - 1 + rr;
            int gc   = side ? (c0 + 64) : (c0 - 1);
            float v0 = 0.f, v1 = 0.f;
            if (gr >= 0 && gr < HH && gc >= 0 && gc < WW) {
                const float* xp = x + ((size_t)(b * CI + ic0 + cp * 2) * HH + gr) * WW + gc;
                v0 = xp[0];
                v1 = xp[HH * WW];
            }
            int col = side ? 65 : 0;
            xs[(rr * 66 + col) * PXS + cp] =
                (int)((unsigned)f2bf(v0) | ((unsigned)f2bf(v1) << 16));
        }
        __syncthreads();
        const short* wfc = wfb + (size_t)ck * WF_CK;
        #pragma unroll
        for (int s = 0; s < 5; ++s) {
            const int xrow = wid + 1 + dh[s];
            const int xc0  = 1 + dw[s];
            v8s af[4];
            #pragma unroll
            for (int mt = 0; mt < 4; ++mt)
                af[mt] = *(const v8s*)(wfc + (size_t)((s * 4 + mt) * 4 + quad) * 128
                                           + l15 * 8);
            #pragma unroll
            for (int nt = 0; nt < 4; ++nt) {
                int px = xrow * 66 + nt * 16 + l15 + xc0;
                v4i bi = *(const v4i*)&xs[px * PXS + quad * 4];
                v8s bfr = __builtin_bit_cast(v8s, bi);
                #pragma unroll
                for (int mt = 0; mt < 4; ++mt)
                    acc[mt][nt] = __builtin_amdgcn_mfma_f32_16x16x32_bf16(
                        af[mt], bfr, acc[mt][nt], 0, 0, 0);
            }
        }
        __syncthreads();
    }
    #pragma unroll
    for (int mt = 0; mt < 4; ++mt)
        #pragma unroll
        for (int nt = 0; nt < 4; ++nt)
            #pragma unroll
            for (int r = 0; r < 4; ++r) {
                int o = oBase + mt * 16 + quad * 4 + r;
                int c = c0 + nt * 16 + l15;
                out[((size_t)(b * CO + o) * HH + row) * WW + c] = acc[mt][nt][r];
            }
}

// ================= R1 min fallback =================
__global__ __launch_bounds__(256) void demod_kernel(const float* __restrict__ y,
                                                    const float* __restrict__ wgt,
                                                    float* __restrict__ dbuf) {
    const int bo = blockIdx.x;
    const int b = bo >> 8, o = bo & 255;
    const int i = threadIdx.x;
    const float* wp = wgt + (o * CI + i) * 5;
    const float ym = y[b * CI + i] + 1.0f;
    float s2 = 0.f;
    #pragma unroll
    for (int s = 0; s < 5; ++s) { float w = wp[s]; s2 += w * w; }
    float val = ym * ym * s2;
    #pragma unroll
    for (int off = 32; off > 0; off >>= 1) val += __shfl_down(val, off);
    __shared__ float red[4];
    if ((threadIdx.x & 63) == 0) red[threadIdx.x >> 6] = val;
    __syncthreads();
    if (threadIdx.x == 0) dbuf[bo] = rsqrtf(red[0] + red[1] + red[2] + red[3] + 1e-6f);
}

__global__ __launch_bounds__(256) void conv_kernel_fb(const float* __restrict__ x,
                                                      const float* __restrict__ y,
                                                      const float* __restrict__ wgt,
                                                      const float* __restrict__ dbuf,
                                                      float* __restrict__ out) {
    const int b     = blockIdx.z;
    const int oBase = blockIdx.y * 64;
    const int st    = blockIdx.x;
    const int r0    = (st >> 1) * 4;
    const int c0    = (st & 1) * 64;
    const int tid  = threadIdx.x;
    const int wid  = tid >> 6;
    const int lane = tid & 63;
    const int l15  = lane & 15;
    const int quad = lane >> 4;
    __shared__ int   xs4[16 * 412];
    __shared__ short wlds[5 * 4 * 4 * 16 * 8];
    v4f acc[4][4];
    #pragma unroll
    for (int a = 0; a < 4; ++a)
        #pragma unroll
        for (int n = 0; n < 4; ++n) acc[a][n] = (v4f){0.f, 0.f, 0.f, 0.f};
    const int row = r0 + wid;
    for (int ic0 = 0; ic0 < CI; ic0 += 32) {
        for (int t = 0; t < 25; ++t) {
            int idx = tid + t * 256;
            if (idx < 6336) {
                int cp  = idx / 396;
                int rem = idx - cp * 396;
                int rr  = rem / 66;
                int cc  = rem - rr * 66;
                int gr  = r0 - 1 + rr;
                int gc  = c0 - 1 + cc;
                float v0 = 0.f, v1 = 0.f;
                if (gr >= 0 && gr < HH && gc >= 0 && gc < WW) {
                    const float* xp = x + ((size_t)(b * CI + ic0 + cp * 2) * HH + gr) * WW + gc;
                    v0 = xp[0];
                    v1 = xp[HH * WW];
                }
                xs4[cp * 412 + rr * 68 + cc] =
                    (int)((unsigned)f2bf(v0) | ((unsigned)f2bf(v1) << 16));
            }
        }
        #pragma unroll
        for (int p = 0; p < 8; ++p) {
            int pidx = tid + p * 256;
            int ol = pidx >> 5;
            int il = pidx & 31;
            int o  = oBase + ol;
            int ci = ic0 + il;
            float scale = (y[b * CI + ci] + 1.0f) * dbuf[b * CO + o];
            const float* wp = wgt + (o * CI + ci) * 5;
            int base = (((ol >> 4) * 4 + (il >> 3)) * 16 + (ol & 15)) * 8 + (il & 7);
            #pragma unroll
            for (int s = 0; s < 5; ++s)
                wlds[base + s * (4 * 4 * 16 * 8)] = (short)f2bf(wp[s] * scale);
        }
        __syncthreads();
        const int dh[5] = {-1, 0, 0, 0, 1};
        const int dw[5] = { 0,-1, 0, 1, 0};
        #pragma unroll
        for (int s = 0; s < 5; ++s) {
            int xrow = wid + 1 + dh[s];
            int xcb  = l15 + 1 + dw[s];
            v8s af[4];
            #pragma unroll
            for (int mt = 0; mt < 4; ++mt)
                af[mt] = *(const v8s*)&wlds[(((s * 4 + mt) * 4 + quad) * 16 + l15) * 8];
            #pragma unroll
            for (int nt = 0; nt < 4; ++nt) {
                v4i bi;
                #pragma unroll
                for (int p = 0; p < 4; ++p)
                    bi[p] = xs4[(quad * 4 + p) * 412 + xrow * 68 + nt * 16 + xcb];
                v8s bfr = __builtin_bit_cast(v8s, bi);
                #pragma unroll
                for (int mt = 0; mt < 4; ++mt)
                    acc[mt][nt] = __builtin_amdgcn_mfma_f32_16x16x32_bf16(
                        af[mt], bfr, acc[mt][nt], 0, 0, 0);
            }
        }
        __syncthreads();
    }
    #pragma unroll
    for (int mt = 0; mt < 4; ++mt)
        #pragma unroll
        for (int nt = 0; nt < 4; ++nt)
            #pragma unroll
            for (int r = 0; r < 4; ++r) {
                int o = oBase + mt * 16 + quad * 4 + r;
                int c = c0 + nt * 16 + l15;
                out[((size_t)(b * CO + o) * HH + row) * WW + c] = acc[mt][nt][r];
            }
}

extern "C" void kernel_launch(void* const* d_in, const int* in_sizes, int n_in,
                              void* d_out, int out_size, void* d_ws, size_t ws_size,
                              hipStream_t stream) {
    const float* x   = (const float*)d_in[0];
    const float* y   = (const float*)d_in[1];
    const float* wgt = (const float*)d_in[2];
    float* out = (float*)d_out;

    const size_t WF_BYTES = (size_t)BS * 4 * 8 * WF_CK * sizeof(short);  // 5.25 MB
    const size_t XT_OFF   = WF_BYTES + 8192;
    const size_t XT_BYTES = (size_t)BS * 8 * 16384 * 64;                 // 64 MB
    const size_t NEED_FULL = XT_OFF + XT_BYTES + 1024;                   // OOB slack
    const size_t NEED_MID  = WF_BYTES + 8192;

    short* wfrag = (short*)d_ws;

    if (ws_size >= NEED_FULL) {
        unsigned int* xt = (unsigned int*)((char*)d_ws + XT_OFF);
        prep_kernel<<<dim3(2048 + BS * 8 * HH), dim3(256), 0, stream>>>(
            x, y, wgt, wfrag, xt);
        conv3_kernel<<<dim3(64, CO / 64, BS), dim3(256), 0, stream>>>(
            (const char*)xt, wfrag, out);
    } else if (ws_size >= NEED_MID) {
        wprep2_kernel<<<dim3(BS * CO), dim3(256), 0, stream>>>(y, wgt, wfrag);
        conv_kernel<<<dim3(64, CO / 64, BS), dim3(256), 0, stream>>>(x, wfrag, out);
    } else {
        float* dbuf = (float*)d_ws;   // 8 KB
        demod_kernel<<<dim3(BS * CO), dim3(256), 0, stream>>>(y, wgt, dbuf);
        conv_kernel_fb<<<dim3(64, CO / 64, BS), dim3(256), 0, stream>>>(x, y, wgt, dbuf, out);
    }
}